// Round 9
// baseline (364.687 us; speedup 1.0000x reference)
//
#include <hip/hip_runtime.h>
#include <hip/hip_cooperative_groups.h>
#include <hip/hip_bf16.h>

namespace cg = cooperative_groups;

#define NSAMP 128
#define AGENTS 64
#define D 128
#define NN (NSAMP * AGENTS)      // 8192
#define LOG2E 1.44269504088896340736f
#define LN2   0.69314718055994530942f
#define EPSF  1e-5f

typedef __attribute__((ext_vector_type(8))) short short8;
typedef __attribute__((ext_vector_type(4))) float floatx4;

__device__ __forceinline__ float u2f(unsigned v) {
    float f; __builtin_memcpy(&f, &v, 4); return f;
}
__device__ __forceinline__ unsigned f2u(float f) {
    unsigned v; __builtin_memcpy(&v, &f, 4); return v;
}
__device__ __forceinline__ unsigned short f2bf(float f) {
    unsigned x; __builtin_memcpy(&x, &f, 4);
    return (unsigned short)((x + 0x7FFFu + ((x >> 16) & 1u)) >> 16);
}

// ===========================================================================
// Shared device helpers (used by both mega and fallback kernels)
// ===========================================================================

// Stage-0 work item t in [0,65): t<64 -> convert one 16-(arr,c)-row weight
// tile to WT[layer][arr][c][k]=Wside[k][c] bf16; t==64 -> zero sacc[512].
__device__ __forceinline__ void do_stage0(
    int t, int tid,
    const float* Wf1, const float* Ws1, const float* Wf2, const float* Ws2,
    unsigned short* WT, float* sacc)
{
    if (t < 64) {
        int rr = t * 16 + (tid >> 4);        // layer*512 + arr*128 + c
        int kk = (tid & 15) * 8;
        int layer = rr >> 9, rem = rr & 511, arr = rem >> 7, c = rem & 127;
        const float* M = (arr < 2) ? (layer ? Wf2 : Wf1) : (layer ? Ws2 : Ws1);
        int side = arr & 1;                  // 0: W rows 0:128 (dst), 1: 128:256 (src)
        short8 sv;
        #pragma unroll
        for (int j = 0; j < 8; ++j)
            sv[j] = (short)f2bf(M[(size_t)(side * 128 + kk + j) * D + c]);
        *(short8*)&WT[(size_t)(layer * 4 + arr) * 16384 + c * 128 + kk] = sv;
    } else {
        sacc[tid]       = 0.f;
        sacc[256 + tid] = 0.f;
    }
}

// One (sample s, col-slice q) prep+edge tile. LDS passed in.
// Layouts (verified): A[m=lane&15][k=quad*8+j]; B[k][n=lane&15] from WT[n][k];
// C/D col=lane&15, row=quad*4+reg.
__device__ __forceinline__ void do_tile(
    int s, int q, int tid,
    const float* __restrict__ xin, const unsigned short* __restrict__ WTl,
    const float* __restrict__ centers,
    const float* __restrict__ Wf, const float* __restrict__ bfp,
    const float* __restrict__ Ws, const float* __restrict__ bsp,
    float* __restrict__ agg, float* __restrict__ sa,
    unsigned int (*EApk)[17], unsigned int (*EBpk)[17])
{
    const int nbase = s * AGENTS;
    const int w = tid >> 6, lane = tid & 63;
    const int quad = lane >> 4, l16 = lane & 15;
    const int col = q * 16 + l16;

    // ---- Phase A: gates via MFMA ----
    short8 a[4];
    {
        const float* xr = xin + (size_t)(nbase + w * 16 + l16) * D + quad * 8;
        #pragma unroll
        for (int kc = 0; kc < 4; ++kc) {
            float4 v0 = *(const float4*)(xr + kc * 32);
            float4 v1 = *(const float4*)(xr + kc * 32 + 4);
            short8 tv;
            tv[0] = (short)f2bf(v0.x); tv[1] = (short)f2bf(v0.y);
            tv[2] = (short)f2bf(v0.z); tv[3] = (short)f2bf(v0.w);
            tv[4] = (short)f2bf(v1.x); tv[5] = (short)f2bf(v1.y);
            tv[6] = (short)f2bf(v1.z); tv[7] = (short)f2bf(v1.w);
            a[kc] = tv;
        }
    }
    floatx4 acc[4];
    #pragma unroll
    for (int arr = 0; arr < 4; ++arr) {
        const unsigned short* wp = WTl + ((size_t)arr * 128 + col) * 128 + quad * 8;
        floatx4 ac = {0.f, 0.f, 0.f, 0.f};
        #pragma unroll
        for (int kc = 0; kc < 4; ++kc)
            ac = __builtin_amdgcn_mfma_f32_16x16x32_bf16(
                a[kc], *(const short8*)(wp + kc * 32), ac, 0, 0, 0);
        acc[arr] = ac;
    }
    const float cwf0 = Wf[256 * D + col], cwf1 = Wf[257 * D + col];
    const float cws0 = Ws[256 * D + col], cws1 = Ws[257 * D + col];
    const float bfv = bfp[col], bsv = bsp[col];
    #pragma unroll
    for (int r = 0; r < 4; ++r) {
        int row = w * 16 + quad * 4 + r;
        int n = nbase + row;
        float ce0 = centers[2 * n], ce1 = centers[2 * n + 1];
        float ctf = fmaf(ce0, cwf0, ce1 * cwf1);
        float cts = fmaf(ce0, cws0, ce1 * cws1);
        unsigned eafu = (unsigned)f2bf(__builtin_amdgcn_exp2f(-LOG2E * (acc[0][r] + ctf + bfv)));
        unsigned easu = (unsigned)f2bf(__builtin_amdgcn_exp2f( LOG2E * (acc[2][r] + cts + bsv)));
        unsigned ebfu = (unsigned)f2bf(__builtin_amdgcn_exp2f(-LOG2E * (acc[1][r] - ctf)));
        unsigned ebsu = (unsigned)f2bf(__builtin_amdgcn_exp2f( LOG2E * (acc[3][r] - cts)));
        EApk[row][l16] = eafu | (easu << 16);
        EBpk[row][l16] = ebfu | (ebsu << 16);
    }
    __syncthreads();

    // ---- Phase B: edge aggregation ----
    const int cl = tid & 15, slot = tid >> 4;
    const int c = q * 16 + cl;
    float eaf[4], eas[4], ac2[4];
    #pragma unroll
    for (int i = 0; i < 4; ++i) {
        unsigned pk = EApk[slot * 4 + i][cl];
        eaf[i] = u2f(pk << 16);
        eas[i] = u2f(pk & 0xFFFF0000u);
        ac2[i] = 0.f;
    }
    #pragma unroll 4
    for (int j = 0; j < 64; ++j) {
        unsigned pk = EBpk[j][cl];
        float ebf = u2f(pk << 16);
        float ebs = u2f(pk & 0xFFFF0000u);
        #pragma unroll
        for (int i = 0; i < 4; ++i) {
            float sg = __builtin_amdgcn_rcpf(fmaf(eaf[i], ebf, 1.f));
            float lg = __builtin_amdgcn_logf(fmaf(eas[i], ebs, 1.f));
            ac2[i] = fmaf(sg, lg, ac2[i]);
        }
    }
    float s1 = 0.f, s2 = 0.f;
    #pragma unroll
    for (int i = 0; i < 4; ++i) {
        int d = slot * 4 + i;
        unsigned pk = EBpk[d][cl];
        float ebf = u2f(pk << 16);
        float ebs = u2f(pk & 0xFFFF0000u);
        float sg = __builtin_amdgcn_rcpf(fmaf(eaf[i], ebf, 1.f));
        float lg = __builtin_amdgcn_logf(fmaf(eas[i], ebs, 1.f));
        float v = (ac2[i] - sg * lg) * LN2;   // exact self-cancel
        agg[(size_t)(nbase + d) * D + c] = v;
        s1 += v; s2 += v * v;
    }
    __syncthreads();                           // gate reads done; reuse LDS
    EApk[slot][cl] = f2u(s1);
    EBpk[slot][cl] = f2u(s2);
    __syncthreads();
    #pragma unroll
    for (int off = 8; off >= 1; off >>= 1) {
        if (slot < off) {
            EApk[slot][cl] = f2u(u2f(EApk[slot][cl]) + u2f(EApk[slot + off][cl]));
            EBpk[slot][cl] = f2u(u2f(EBpk[slot][cl]) + u2f(EBpk[slot + off][cl]));
        }
        __syncthreads();
    }
    if (slot == 0) {
        atomicAdd(&sa[c],       u2f(EApk[0][cl]));
        atomicAdd(&sa[128 + c], u2f(EBpk[0][cl]));
    }
}

// BN element group (8 floats) at quad-index idx.
__device__ __forceinline__ void do_bn(
    int idx, const float* __restrict__ agg, const float* __restrict__ xin,
    const float* __restrict__ sa, const float* __restrict__ gm,
    const float* __restrict__ bt, float* __restrict__ dst)
{
    const int n = idx >> 5;
    const int c4 = (idx & 31) * 4;
    size_t off = (size_t)n * D + c4;
    const float inv = 1.f / NN;
    float4 av  = *(const float4*)&agg[off];
    float4 xv  = *(const float4*)&xin[off];
    float4 s1v = *(const float4*)&sa[c4];
    float4 s2v = *(const float4*)&sa[128 + c4];
    float4 gmv = *(const float4*)&gm[c4];
    float4 btv = *(const float4*)&bt[c4];
    float4 o;
    float mu, var, rs;
    mu = s1v.x * inv; var = s2v.x * inv - mu * mu; rs = rsqrtf(var + EPSF);
    o.x = fmaxf(0.f, fmaf((av.x - mu) * rs, gmv.x, btv.x) + xv.x);
    mu = s1v.y * inv; var = s2v.y * inv - mu * mu; rs = rsqrtf(var + EPSF);
    o.y = fmaxf(0.f, fmaf((av.y - mu) * rs, gmv.y, btv.y) + xv.y);
    mu = s1v.z * inv; var = s2v.z * inv - mu * mu; rs = rsqrtf(var + EPSF);
    o.z = fmaxf(0.f, fmaf((av.z - mu) * rs, gmv.z, btv.z) + xv.z);
    mu = s1v.w * inv; var = s2v.w * inv - mu * mu; rs = rsqrtf(var + EPSF);
    o.w = fmaxf(0.f, fmaf((av.w - mu) * rs, gmv.w, btv.w) + xv.w);
    *(float4*)&dst[off] = o;
}

// ===========================================================================
// Cooperative mega-kernel: fully grid-stride, any grid size is correct.
// ===========================================================================
__global__ __launch_bounds__(256, 4) void mega_kernel(
    const float* __restrict__ x0, const float* __restrict__ centers,
    const float* __restrict__ Wf1, const float* __restrict__ bf1,
    const float* __restrict__ Ws1, const float* __restrict__ bs1,
    const float* __restrict__ gm1, const float* __restrict__ bt1,
    const float* __restrict__ Wf2, const float* __restrict__ bf2,
    const float* __restrict__ Ws2, const float* __restrict__ bs2,
    const float* __restrict__ gm2, const float* __restrict__ bt2,
    unsigned short* __restrict__ WT, float* __restrict__ agg,
    float* __restrict__ x1, float* __restrict__ sacc,
    float* __restrict__ outp)
{
    cg::grid_group grid = cg::this_grid();
    const int NB = gridDim.x, b = blockIdx.x, tid = threadIdx.x;

    __shared__ unsigned int EApk[64][17];
    __shared__ unsigned int EBpk[64][17];

    for (int t = b; t < 65; t += NB)
        do_stage0(t, tid, Wf1, Ws1, Wf2, Ws2, WT, sacc);
    grid.sync();

    for (int layer = 0; layer < 2; ++layer) {
        const float* xin = layer ? x1 : x0;
        const unsigned short* WTl = WT + (size_t)layer * 65536;
        const float* Wf = layer ? Wf2 : Wf1;
        const float* Ws = layer ? Ws2 : Ws1;
        const float* bfp = layer ? bf2 : bf1;
        const float* bsp = layer ? bs2 : bs1;
        float* sa = sacc + layer * 256;

        for (int t = b; t < 1024; t += NB) {
            __syncthreads();   // protect LDS reuse across tile iterations
            do_tile(t >> 3, t & 7, tid, xin, WTl, centers,
                    Wf, bfp, Ws, bsp, agg, sa, EApk, EBpk);
        }
        grid.sync();

        const float* gm = layer ? gm2 : gm1;
        const float* bt = layer ? bt2 : bt1;
        float* dst = layer ? outp : x1;
        for (int idx = b * 256 + tid; idx < NN * D / 4; idx += NB * 256)
            do_bn(idx, agg, xin, sa, gm, bt, dst);
        if (layer == 0) grid.sync();
    }
}

// ===========================================================================
// Fallback kernels (R7 pipeline, proven correct at 148 us)
// ===========================================================================
__global__ __launch_bounds__(256) void cvt_kernel(
    const float* __restrict__ Wf1, const float* __restrict__ Ws1,
    const float* __restrict__ Wf2, const float* __restrict__ Ws2,
    unsigned short* __restrict__ WT, float* __restrict__ sacc)
{
    do_stage0(blockIdx.x, threadIdx.x, Wf1, Ws1, Wf2, Ws2, WT, sacc);
}

__global__ __launch_bounds__(256, 4) void prep_edge(
    const float* __restrict__ xin, const unsigned short* __restrict__ WTl,
    const float* __restrict__ centers,
    const float* __restrict__ Wf, const float* __restrict__ bfp,
    const float* __restrict__ Ws, const float* __restrict__ bsp,
    float* __restrict__ agg, float* __restrict__ sa)
{
    __shared__ unsigned int EApk[64][17];
    __shared__ unsigned int EBpk[64][17];
    do_tile(blockIdx.x >> 3, blockIdx.x & 7, threadIdx.x, xin, WTl, centers,
            Wf, bfp, Ws, bsp, agg, sa, EApk, EBpk);
}

__global__ __launch_bounds__(256) void bn_kernel(
    const float* __restrict__ agg, const float* __restrict__ xin,
    const float* __restrict__ sa,
    const float* __restrict__ gm, const float* __restrict__ bt,
    float* __restrict__ outp)
{
    do_bn(blockIdx.x * 256 + threadIdx.x, agg, xin, sa, gm, bt, outp);
}

// ===========================================================================
extern "C" void kernel_launch(void* const* d_in, const int* in_sizes, int n_in,
                              void* d_out, int out_size, void* d_ws, size_t ws_size,
                              hipStream_t stream) {
    const float* x0      = (const float*)d_in[0];
    const float* centers = (const float*)d_in[1];
    // d_in[2], d_in[3]: edge lists — clique structure is deterministic, unused.
    const float* Wf1 = (const float*)d_in[4];
    const float* bf1 = (const float*)d_in[5];
    const float* Ws1 = (const float*)d_in[6];
    const float* bs1 = (const float*)d_in[7];
    const float* gm1 = (const float*)d_in[8];
    const float* bt1 = (const float*)d_in[9];
    const float* Wf2 = (const float*)d_in[10];
    const float* bf2 = (const float*)d_in[11];
    const float* Ws2 = (const float*)d_in[12];
    const float* bs2 = (const float*)d_in[13];
    const float* gm2 = (const float*)d_in[14];
    const float* bt2 = (const float*)d_in[15];

    const size_t ND = (size_t)NN * D;              // 1048576
    unsigned short* ws_u = (unsigned short*)d_ws;
    unsigned short* WT = ws_u;                     // 2 x 65536 bf16
    float* fbase = (float*)(WT + 2 * 65536);       // 16B-aligned
    float* agg   = fbase;                          // ND
    float* x1    = fbase + ND;                     // ND
    float* sacc  = fbase + 2 * ND;                 // 2 layers x 256

    float* outp = (float*)d_out;

    // Try cooperative path, sized by queried occupancy (deterministic).
    int maxblk = 0;
    (void)hipOccupancyMaxActiveBlocksPerMultiprocessor(&maxblk, mega_kernel, 256, 0);
    bool coop_done = false;
    if (maxblk >= 1) {
        int nb = maxblk * 256;                     // 256 CUs on MI355X
        if (nb > 1024) nb = 1024;
        void* args[] = {
            (void*)&x0, (void*)&centers,
            (void*)&Wf1, (void*)&bf1, (void*)&Ws1, (void*)&bs1,
            (void*)&gm1, (void*)&bt1,
            (void*)&Wf2, (void*)&bf2, (void*)&Ws2, (void*)&bs2,
            (void*)&gm2, (void*)&bt2,
            (void*)&WT, (void*)&agg, (void*)&x1, (void*)&sacc, (void*)&outp
        };
        hipError_t e = hipLaunchCooperativeKernel((void*)mega_kernel, dim3(nb),
                                                  dim3(256), args, 0, stream);
        coop_done = (e == hipSuccess);
    }

    if (!coop_done) {
        // Fallback: R7 pipeline.
        cvt_kernel<<<dim3(65), dim3(256), 0, stream>>>(
            Wf1, Ws1, Wf2, Ws2, WT, sacc);
        prep_edge<<<dim3(1024), dim3(256), 0, stream>>>(
            x0, WT, centers, Wf1, bf1, Ws1, bs1, agg, sacc);
        bn_kernel<<<dim3(512), dim3(256), 0, stream>>>(
            agg, x0, sacc, gm1, bt1, x1);
        prep_edge<<<dim3(1024), dim3(256), 0, stream>>>(
            x1, WT + 65536, centers, Wf2, bf2, Ws2, bs2, agg, sacc + 256);
        bn_kernel<<<dim3(512), dim3(256), 0, stream>>>(
            agg, x1, sacc + 256, gm2, bt2, outp);
    }
}

// Round 10
// 154.691 us; speedup vs baseline: 2.3575x; 2.3575x over previous
//
#include <hip/hip_runtime.h>
#include <hip/hip_bf16.h>

#define NSAMP 128
#define AGENTS 64
#define D 128
#define NN (NSAMP * AGENTS)      // 8192
#define LOG2E 1.44269504088896340736f
#define LN2   0.69314718055994530942f
#define EPSF  1e-5f

typedef __attribute__((ext_vector_type(8))) short short8;
typedef __attribute__((ext_vector_type(4))) float floatx4;

__device__ __forceinline__ float u2f(unsigned v) {
    float f; __builtin_memcpy(&f, &v, 4); return f;
}
__device__ __forceinline__ unsigned f2u(float f) {
    unsigned v; __builtin_memcpy(&v, &f, 4); return v;
}
__device__ __forceinline__ unsigned short f2bf(float f) {
    unsigned x; __builtin_memcpy(&x, &f, 4);
    return (unsigned short)((x + 0x7FFFu + ((x >> 16) & 1u)) >> 16);
}

// ---------------------------------------------------------------------------
// K0: build transposed bf16 weights WT[layer][arr][c][k]=Wside[k][c];
//     arr: 0=Af(dst) 1=Bf(src) 2=As(dst) 3=Bs(src). Block 64 zeros sacc.
// grid 65 x 256.
// ---------------------------------------------------------------------------
__global__ __launch_bounds__(256) void cvt_kernel(
    const float* __restrict__ Wf1, const float* __restrict__ Ws1,
    const float* __restrict__ Wf2, const float* __restrict__ Ws2,
    unsigned short* __restrict__ WT, float* __restrict__ sacc)
{
    int t = blockIdx.x, tid = threadIdx.x;
    if (t < 64) {
        int rr = t * 16 + (tid >> 4);        // layer*512 + arr*128 + c
        int kk = (tid & 15) * 8;
        int layer = rr >> 9, rem = rr & 511, arr = rem >> 7, c = rem & 127;
        const float* M = (arr < 2) ? (layer ? Wf2 : Wf1) : (layer ? Ws2 : Ws1);
        int side = arr & 1;                  // 0: W rows 0:128 (dst), 1: 128:256 (src)
        short8 sv;
        #pragma unroll
        for (int j = 0; j < 8; ++j)
            sv[j] = (short)f2bf(M[(size_t)(side * 128 + kk + j) * D + c]);
        *(short8*)&WT[(size_t)(layer * 4 + arr) * 16384 + c * 128 + kk] = sv;
    } else {
        sacc[tid]       = 0.f;
        sacc[256 + tid] = 0.f;
    }
}

// ---------------------------------------------------------------------------
// K1: fused prep (MFMA) + edge aggregation, channel-sliced, 512-thread blocks
// for 100% occupancy (grid 1024 = 4 blocks/CU x 8 waves = 32 waves/CU).
// Block = (sample s, 16-col slice q).
// Phase A: 8 waves; wave w -> mtile (w&3) [16 rows], pair (w>>2):
//   pair 0: EB gates (arrs 1=Bf,3=Bs, -center term) -> EBpk[row][cl]
//   pair 1: EA gates (arrs 0=Af,2=As, +center,+bias) -> EApk[row][cl]
//   8 MFMAs/wave (16x16x32 bf16); packed bf16 pairs (low=f, high=s).
//   Layouts (verified): A[m=lane&15][k=quad*8+j]; B[k][n=lane&15] from
//   WT[n][k]; C/D col=lane&15, row=quad*4+reg.
// Phase B: thread=(cl, slot 0..31), 2 dst rows each; j-loop over 64 src:
//   agg[d][c] = sum_{j!=d} rcp(1+EAf*EBf)*log2(1+EAs*EBs)*ln2
//   (full sum, exact self-cancel). Stats: 32-slot tree -> atomicAdd sacc.
// ---------------------------------------------------------------------------
__global__ __launch_bounds__(512, 8) void prep_edge(
    const float* __restrict__ xin,           // [NN][128] fp32
    const unsigned short* __restrict__ WTl,  // [4][128][128] bf16, this layer
    const float* __restrict__ centers,       // [NN][2]
    const float* __restrict__ Wf, const float* __restrict__ bfp,
    const float* __restrict__ Ws, const float* __restrict__ bsp,
    float* __restrict__ agg,                 // [NN][D] fp32
    float* __restrict__ sa)                  // [2][128] s1,s2
{
    const int s = blockIdx.x >> 3, q = blockIdx.x & 7;
    const int nbase = s * AGENTS;
    const int tid = threadIdx.x;
    const int w = tid >> 6, lane = tid & 63;
    const int quad = lane >> 4, l16 = lane & 15;
    const int m = w & 3, pair = w >> 2;
    const int col = q * 16 + l16;

    __shared__ unsigned int EApk[64][17];
    __shared__ unsigned int EBpk[64][17];

    // ---- Phase A ----
    short8 a[4];
    {
        const float* xr = xin + (size_t)(nbase + m * 16 + l16) * D + quad * 8;
        #pragma unroll
        for (int kc = 0; kc < 4; ++kc) {
            float4 v0 = *(const float4*)(xr + kc * 32);
            float4 v1 = *(const float4*)(xr + kc * 32 + 4);
            short8 tv;
            tv[0] = (short)f2bf(v0.x); tv[1] = (short)f2bf(v0.y);
            tv[2] = (short)f2bf(v0.z); tv[3] = (short)f2bf(v0.w);
            tv[4] = (short)f2bf(v1.x); tv[5] = (short)f2bf(v1.y);
            tv[6] = (short)f2bf(v1.z); tv[7] = (short)f2bf(v1.w);
            a[kc] = tv;
        }
    }
    // arrays: pair 0 -> {1,3} (Bf,Bs); pair 1 -> {0,2} (Af,As)
    const int arrF = pair ? 0 : 1, arrS = pair ? 2 : 3;
    floatx4 accF = {0.f,0.f,0.f,0.f}, accS = {0.f,0.f,0.f,0.f};
    {
        const unsigned short* wpF = WTl + ((size_t)arrF * 128 + col) * 128 + quad * 8;
        const unsigned short* wpS = WTl + ((size_t)arrS * 128 + col) * 128 + quad * 8;
        #pragma unroll
        for (int kc = 0; kc < 4; ++kc) {
            accF = __builtin_amdgcn_mfma_f32_16x16x32_bf16(
                a[kc], *(const short8*)(wpF + kc * 32), accF, 0, 0, 0);
            accS = __builtin_amdgcn_mfma_f32_16x16x32_bf16(
                a[kc], *(const short8*)(wpS + kc * 32), accS, 0, 0, 0);
        }
    }
    {
        const float cwf0 = Wf[256 * D + col], cwf1 = Wf[257 * D + col];
        const float cws0 = Ws[256 * D + col], cws1 = Ws[257 * D + col];
        const float bfv = bfp[col], bsv = bsp[col];
        #pragma unroll
        for (int r = 0; r < 4; ++r) {
            int row = m * 16 + quad * 4 + r;
            int n = nbase + row;
            float ce0 = centers[2 * n], ce1 = centers[2 * n + 1];
            float ctf = fmaf(ce0, cwf0, ce1 * cwf1);
            float cts = fmaf(ce0, cws0, ce1 * cws1);
            if (pair) {  // EA: dst gates (+center, +bias)
                unsigned uf = (unsigned)f2bf(__builtin_amdgcn_exp2f(-LOG2E * (accF[r] + ctf + bfv)));
                unsigned us = (unsigned)f2bf(__builtin_amdgcn_exp2f( LOG2E * (accS[r] + cts + bsv)));
                EApk[row][l16] = uf | (us << 16);
            } else {     // EB: src gates (-center)
                unsigned uf = (unsigned)f2bf(__builtin_amdgcn_exp2f(-LOG2E * (accF[r] - ctf)));
                unsigned us = (unsigned)f2bf(__builtin_amdgcn_exp2f( LOG2E * (accS[r] - cts)));
                EBpk[row][l16] = uf | (us << 16);
            }
        }
    }
    __syncthreads();

    // ---- Phase B: thread=(cl, slot 0..31), 2 dst rows ----
    const int cl = tid & 15, slot = tid >> 4;
    const int c = q * 16 + cl;
    float eaf[2], eas[2], ac2[2];
    #pragma unroll
    for (int i = 0; i < 2; ++i) {
        unsigned pk = EApk[slot * 2 + i][cl];
        eaf[i] = u2f(pk << 16);
        eas[i] = u2f(pk & 0xFFFF0000u);
        ac2[i] = 0.f;
    }
    #pragma unroll 8
    for (int j = 0; j < 64; ++j) {
        unsigned pk = EBpk[j][cl];
        float ebf = u2f(pk << 16);
        float ebs = u2f(pk & 0xFFFF0000u);
        #pragma unroll
        for (int i = 0; i < 2; ++i) {
            float sg = __builtin_amdgcn_rcpf(fmaf(eaf[i], ebf, 1.f));
            float lg = __builtin_amdgcn_logf(fmaf(eas[i], ebs, 1.f));
            ac2[i] = fmaf(sg, lg, ac2[i]);
        }
    }
    float s1 = 0.f, s2 = 0.f;
    #pragma unroll
    for (int i = 0; i < 2; ++i) {
        int d = slot * 2 + i;
        unsigned pk = EBpk[d][cl];
        float ebf = u2f(pk << 16);
        float ebs = u2f(pk & 0xFFFF0000u);
        float sg = __builtin_amdgcn_rcpf(fmaf(eaf[i], ebf, 1.f));
        float lg = __builtin_amdgcn_logf(fmaf(eas[i], ebs, 1.f));
        float v = (ac2[i] - sg * lg) * LN2;   // exact self-cancel
        agg[(size_t)(nbase + d) * D + c] = v;
        s1 += v; s2 += v * v;
    }
    __syncthreads();                           // gate reads done; reuse LDS
    EApk[slot][cl] = f2u(s1);
    EBpk[slot][cl] = f2u(s2);
    __syncthreads();
    #pragma unroll
    for (int off = 16; off >= 1; off >>= 1) {
        if (slot < off) {
            EApk[slot][cl] = f2u(u2f(EApk[slot][cl]) + u2f(EApk[slot + off][cl]));
            EBpk[slot][cl] = f2u(u2f(EBpk[slot][cl]) + u2f(EBpk[slot + off][cl]));
        }
        __syncthreads();
    }
    if (slot == 0) {
        atomicAdd(&sa[c],       u2f(EApk[0][cl]));
        atomicAdd(&sa[128 + c], u2f(EBpk[0][cl]));
    }
}

// ---------------------------------------------------------------------------
// K2: BN + residual + relu from raw sums -> fp32 out. grid 512 x 256.
// ---------------------------------------------------------------------------
__global__ __launch_bounds__(256) void bn_kernel(
    const float* __restrict__ agg, const float* __restrict__ xin,
    const float* __restrict__ sa,
    const float* __restrict__ gm, const float* __restrict__ bt,
    float* __restrict__ outp)
{
    const int idx = blockIdx.x * 256 + threadIdx.x;
    const int n = idx >> 4;
    const int c = (idx & 15) * 8;
    size_t off = (size_t)n * D + c;
    const float inv = 1.f / NN;
    float v[8];
    #pragma unroll
    for (int h = 0; h < 2; ++h) {
        float4 av  = *(const float4*)&agg[off + h * 4];
        float4 xv  = *(const float4*)&xin[off + h * 4];
        float4 s1v = *(const float4*)&sa[c + h * 4];
        float4 s2v = *(const float4*)&sa[128 + c + h * 4];
        float4 gmv = *(const float4*)&gm[c + h * 4];
        float4 btv = *(const float4*)&bt[c + h * 4];
        float mu, var, rs;
        mu = s1v.x * inv; var = s2v.x * inv - mu * mu; rs = rsqrtf(var + EPSF);
        v[h*4+0] = fmaxf(0.f, fmaf((av.x - mu) * rs, gmv.x, btv.x) + xv.x);
        mu = s1v.y * inv; var = s2v.y * inv - mu * mu; rs = rsqrtf(var + EPSF);
        v[h*4+1] = fmaxf(0.f, fmaf((av.y - mu) * rs, gmv.y, btv.y) + xv.y);
        mu = s1v.z * inv; var = s2v.z * inv - mu * mu; rs = rsqrtf(var + EPSF);
        v[h*4+2] = fmaxf(0.f, fmaf((av.z - mu) * rs, gmv.z, btv.z) + xv.z);
        mu = s1v.w * inv; var = s2v.w * inv - mu * mu; rs = rsqrtf(var + EPSF);
        v[h*4+3] = fmaxf(0.f, fmaf((av.w - mu) * rs, gmv.w, btv.w) + xv.w);
    }
    *(float4*)&outp[off]     = *(float4*)&v[0];
    *(float4*)&outp[off + 4] = *(float4*)&v[4];
}

// ---------------------------------------------------------------------------
extern "C" void kernel_launch(void* const* d_in, const int* in_sizes, int n_in,
                              void* d_out, int out_size, void* d_ws, size_t ws_size,
                              hipStream_t stream) {
    const float* x0      = (const float*)d_in[0];
    const float* centers = (const float*)d_in[1];
    // d_in[2], d_in[3]: edge lists — clique structure is deterministic, unused.
    const float* Wf1 = (const float*)d_in[4];
    const float* bf1 = (const float*)d_in[5];
    const float* Ws1 = (const float*)d_in[6];
    const float* bs1 = (const float*)d_in[7];
    const float* gm1 = (const float*)d_in[8];
    const float* bt1 = (const float*)d_in[9];
    const float* Wf2 = (const float*)d_in[10];
    const float* bf2 = (const float*)d_in[11];
    const float* Ws2 = (const float*)d_in[12];
    const float* bs2 = (const float*)d_in[13];
    const float* gm2 = (const float*)d_in[14];
    const float* bt2 = (const float*)d_in[15];

    const size_t ND = (size_t)NN * D;              // 1048576
    unsigned short* ws_u = (unsigned short*)d_ws;
    unsigned short* WT = ws_u;                     // 2 x 65536 bf16
    float* fbase = (float*)(WT + 2 * 65536);       // 16B-aligned
    float* agg   = fbase;                          // ND
    float* x1    = fbase + ND;                     // ND
    float* sacc  = fbase + 2 * ND;                 // 2 layers x 256

    float* outp = (float*)d_out;

    cvt_kernel<<<dim3(65), dim3(256), 0, stream>>>(
        Wf1, Ws1, Wf2, Ws2, WT, sacc);

    // Layer 1
    prep_edge<<<dim3(1024), dim3(512), 0, stream>>>(
        x0, WT, centers, Wf1, bf1, Ws1, bs1, agg, sacc);
    bn_kernel<<<dim3(512), dim3(256), 0, stream>>>(
        agg, x0, sacc, gm1, bt1, x1);

    // Layer 2
    prep_edge<<<dim3(1024), dim3(512), 0, stream>>>(
        x1, WT + 65536, centers, Wf2, bf2, Ws2, bs2, agg, sacc + 256);
    bn_kernel<<<dim3(512), dim3(256), 0, stream>>>(
        agg, x1, sacc + 256, gm2, bt2, outp);
}

// Round 11
// 153.258 us; speedup vs baseline: 2.3796x; 1.0093x over previous
//
#include <hip/hip_runtime.h>
#include <hip/hip_bf16.h>

#define NSAMP 128
#define AGENTS 64
#define D 128
#define NN (NSAMP * AGENTS)      // 8192
#define LOG2E 1.44269504088896340736f
#define LN2   0.69314718055994530942f
#define EPSF  1e-5f

typedef __attribute__((ext_vector_type(8))) short short8;
typedef __attribute__((ext_vector_type(4))) float floatx4;

__device__ __forceinline__ float u2f(unsigned v) {
    float f; __builtin_memcpy(&f, &v, 4); return f;
}
__device__ __forceinline__ unsigned f2u(float f) {
    unsigned v; __builtin_memcpy(&v, &f, 4); return v;
}
__device__ __forceinline__ unsigned short f2bf(float f) {
    unsigned x; __builtin_memcpy(&x, &f, 4);
    return (unsigned short)((x + 0x7FFFu + ((x >> 16) & 1u)) >> 16);
}

// ---------------------------------------------------------------------------
// K0: build transposed bf16 weights WT[layer][arr][c][k]=Wside[k][c];
//     arr: 0=Af(dst) 1=Bf(src) 2=As(dst) 3=Bs(src). Block 64 zeros sacc.
// grid 65 x 256.
// ---------------------------------------------------------------------------
__global__ __launch_bounds__(256) void cvt_kernel(
    const float* __restrict__ Wf1, const float* __restrict__ Ws1,
    const float* __restrict__ Wf2, const float* __restrict__ Ws2,
    unsigned short* __restrict__ WT, float* __restrict__ sacc)
{
    int t = blockIdx.x, tid = threadIdx.x;
    if (t < 64) {
        int rr = t * 16 + (tid >> 4);        // layer*512 + arr*128 + c
        int kk = (tid & 15) * 8;
        int layer = rr >> 9, rem = rr & 511, arr = rem >> 7, c = rem & 127;
        const float* M = (arr < 2) ? (layer ? Wf2 : Wf1) : (layer ? Ws2 : Ws1);
        int side = arr & 1;                  // 0: W rows 0:128 (dst), 1: 128:256 (src)
        short8 sv;
        #pragma unroll
        for (int j = 0; j < 8; ++j)
            sv[j] = (short)f2bf(M[(size_t)(side * 128 + kk + j) * D + c]);
        *(short8*)&WT[(size_t)(layer * 4 + arr) * 16384 + c * 128 + kk] = sv;
    } else {
        sacc[tid]       = 0.f;
        sacc[256 + tid] = 0.f;
    }
}

// ---------------------------------------------------------------------------
// K1: fused prep (MFMA) + edge aggregation, channel-sliced (R7-proven shape:
// 256 threads, grid 1024 = (sample s, 16-col slice q), 4 blocks/CU).
// Optional fused BN of the PREVIOUS layer on the A-load:
//   x = relu(fmaf(agg, scale[k], shift[k]) + x0), scale/shift precomputed per
//   block from sacc_prev/gamma/beta (128 rsqrt, LDS); q==0 blocks write x1.
// Phase A: wave w -> mtile w (16 rows) x 16 cols x all 4 gate arrays via
//   MFMA 16x16x32 bf16; exp2 -> packed bf16 pairs in LDS
//   (EApk: dst gates +center+bias; EBpk: src gates -center).
//   Layouts (verified): A[m=lane&15][k=quad*8+j]; B[k][n=lane&15] from
//   WT[n][k]; C/D col=lane&15, row=quad*4+reg.
// Phase B: thread=(cl, slot), 4 dst rows; j-loop over 64 src rows:
//   agg[d][c] = sum_{j!=d} rcp(1+EAf*EBf)*log2(1+EAs*EBs)*ln2
//   (full sum, exact self-cancel). Stats tree -> atomicAdd sacc.
// ---------------------------------------------------------------------------
__global__ __launch_bounds__(256, 4) void prep_edge(
    const float* __restrict__ xbase,         // [NN][128] fp32 (x0)
    const float* __restrict__ aggin,         // [NN][128] prev-layer agg or null
    const float* __restrict__ sap,           // prev sacc (when fused)
    const float* __restrict__ gmp, const float* __restrict__ btp,
    float* __restrict__ x1out,               // fused: q==0 writes BN result
    const unsigned short* __restrict__ WTl,  // [4][128][128] bf16, this layer
    const float* __restrict__ centers,       // [NN][2]
    const float* __restrict__ Wf, const float* __restrict__ bfp,
    const float* __restrict__ Ws, const float* __restrict__ bsp,
    float* __restrict__ agg,                 // [NN][D] fp32 out
    float* __restrict__ sa)                  // [2][128] s1,s2 out
{
    const int s = blockIdx.x >> 3, q = blockIdx.x & 7;
    const int nbase = s * AGENTS;
    const int tid = threadIdx.x;
    const int w = tid >> 6, lane = tid & 63;
    const int quad = lane >> 4, l16 = lane & 15;
    const int col = q * 16 + l16;
    const bool fuse = (aggin != nullptr);

    __shared__ unsigned int EApk[64][17];
    __shared__ unsigned int EBpk[64][17];
    __shared__ float scaleL[128], shiftL[128];

    if (fuse) {
        if (tid < 128) {
            const float inv = 1.f / NN;
            float mu = sap[tid] * inv;
            float var = sap[128 + tid] * inv - mu * mu;
            float rs = rsqrtf(var + EPSF);
            float sc = rs * gmp[tid];
            scaleL[tid] = sc;
            shiftL[tid] = btp[tid] - mu * sc;
        }
        __syncthreads();
    }

    // ---- Phase A ----
    const int row = w * 16 + l16;            // sample-local row this lane loads
    short8 a[4];
    {
        const float* xr = xbase + (size_t)(nbase + row) * D + quad * 8;
        const float* ar = fuse ? aggin + (size_t)(nbase + row) * D + quad * 8 : nullptr;
        float* x1r = x1out + (size_t)(nbase + row) * D + quad * 8;
        #pragma unroll
        for (int kc = 0; kc < 4; ++kc) {
            float4 v0 = *(const float4*)(xr + kc * 32);
            float4 v1 = *(const float4*)(xr + kc * 32 + 4);
            if (fuse) {
                float4 a0 = *(const float4*)(ar + kc * 32);
                float4 a1 = *(const float4*)(ar + kc * 32 + 4);
                const int k0 = quad * 8 + kc * 32;
                v0.x = fmaxf(0.f, fmaf(a0.x, scaleL[k0+0], shiftL[k0+0]) + v0.x);
                v0.y = fmaxf(0.f, fmaf(a0.y, scaleL[k0+1], shiftL[k0+1]) + v0.y);
                v0.z = fmaxf(0.f, fmaf(a0.z, scaleL[k0+2], shiftL[k0+2]) + v0.z);
                v0.w = fmaxf(0.f, fmaf(a0.w, scaleL[k0+3], shiftL[k0+3]) + v0.w);
                v1.x = fmaxf(0.f, fmaf(a1.x, scaleL[k0+4], shiftL[k0+4]) + v1.x);
                v1.y = fmaxf(0.f, fmaf(a1.y, scaleL[k0+5], shiftL[k0+5]) + v1.y);
                v1.z = fmaxf(0.f, fmaf(a1.z, scaleL[k0+6], shiftL[k0+6]) + v1.z);
                v1.w = fmaxf(0.f, fmaf(a1.w, scaleL[k0+7], shiftL[k0+7]) + v1.w);
                if (q == 0) {
                    *(float4*)(x1r + kc * 32)     = v0;
                    *(float4*)(x1r + kc * 32 + 4) = v1;
                }
            }
            short8 tv;
            tv[0] = (short)f2bf(v0.x); tv[1] = (short)f2bf(v0.y);
            tv[2] = (short)f2bf(v0.z); tv[3] = (short)f2bf(v0.w);
            tv[4] = (short)f2bf(v1.x); tv[5] = (short)f2bf(v1.y);
            tv[6] = (short)f2bf(v1.z); tv[7] = (short)f2bf(v1.w);
            a[kc] = tv;
        }
    }
    floatx4 acc[4];
    #pragma unroll
    for (int arr = 0; arr < 4; ++arr) {
        const unsigned short* wp = WTl + ((size_t)arr * 128 + col) * 128 + quad * 8;
        floatx4 ac = {0.f, 0.f, 0.f, 0.f};
        #pragma unroll
        for (int kc = 0; kc < 4; ++kc)
            ac = __builtin_amdgcn_mfma_f32_16x16x32_bf16(
                a[kc], *(const short8*)(wp + kc * 32), ac, 0, 0, 0);
        acc[arr] = ac;
    }
    {
        const float cwf0 = Wf[256 * D + col], cwf1 = Wf[257 * D + col];
        const float cws0 = Ws[256 * D + col], cws1 = Ws[257 * D + col];
        const float bfv = bfp[col], bsv = bsp[col];
        #pragma unroll
        for (int r = 0; r < 4; ++r) {
            int rw = w * 16 + quad * 4 + r;
            int n = nbase + rw;
            float ce0 = centers[2 * n], ce1 = centers[2 * n + 1];
            float ctf = fmaf(ce0, cwf0, ce1 * cwf1);
            float cts = fmaf(ce0, cws0, ce1 * cws1);
            unsigned eafu = (unsigned)f2bf(__builtin_amdgcn_exp2f(-LOG2E * (acc[0][r] + ctf + bfv)));
            unsigned easu = (unsigned)f2bf(__builtin_amdgcn_exp2f( LOG2E * (acc[2][r] + cts + bsv)));
            unsigned ebfu = (unsigned)f2bf(__builtin_amdgcn_exp2f(-LOG2E * (acc[1][r] - ctf)));
            unsigned ebsu = (unsigned)f2bf(__builtin_amdgcn_exp2f( LOG2E * (acc[3][r] - cts)));
            EApk[rw][l16] = eafu | (easu << 16);
            EBpk[rw][l16] = ebfu | (ebsu << 16);
        }
    }
    __syncthreads();

    // ---- Phase B: thread=(cl, slot 0..15), 4 dst rows ----
    const int cl = tid & 15, slot = tid >> 4;
    const int c = q * 16 + cl;
    float eaf[4], eas[4], ac2[4];
    #pragma unroll
    for (int i = 0; i < 4; ++i) {
        unsigned pk = EApk[slot * 4 + i][cl];
        eaf[i] = u2f(pk << 16);
        eas[i] = u2f(pk & 0xFFFF0000u);
        ac2[i] = 0.f;
    }
    #pragma unroll 4
    for (int j = 0; j < 64; ++j) {
        unsigned pk = EBpk[j][cl];
        float ebf = u2f(pk << 16);
        float ebs = u2f(pk & 0xFFFF0000u);
        #pragma unroll
        for (int i = 0; i < 4; ++i) {
            float sg = __builtin_amdgcn_rcpf(fmaf(eaf[i], ebf, 1.f));
            float lg = __builtin_amdgcn_logf(fmaf(eas[i], ebs, 1.f));
            ac2[i] = fmaf(sg, lg, ac2[i]);
        }
    }
    float s1 = 0.f, s2 = 0.f;
    #pragma unroll
    for (int i = 0; i < 4; ++i) {
        int d = slot * 4 + i;
        unsigned pk = EBpk[d][cl];
        float ebf = u2f(pk << 16);
        float ebs = u2f(pk & 0xFFFF0000u);
        float sg = __builtin_amdgcn_rcpf(fmaf(eaf[i], ebf, 1.f));
        float lg = __builtin_amdgcn_logf(fmaf(eas[i], ebs, 1.f));
        float v = (ac2[i] - sg * lg) * LN2;   // exact self-cancel
        agg[(size_t)(nbase + d) * D + c] = v;
        s1 += v; s2 += v * v;
    }
    __syncthreads();                           // gate reads done; reuse LDS
    EApk[slot][cl] = f2u(s1);
    EBpk[slot][cl] = f2u(s2);
    __syncthreads();
    #pragma unroll
    for (int off = 8; off >= 1; off >>= 1) {
        if (slot < off) {
            EApk[slot][cl] = f2u(u2f(EApk[slot][cl]) + u2f(EApk[slot + off][cl]));
            EBpk[slot][cl] = f2u(u2f(EBpk[slot][cl]) + u2f(EBpk[slot + off][cl]));
        }
        __syncthreads();
    }
    if (slot == 0) {
        atomicAdd(&sa[c],       u2f(EApk[0][cl]));
        atomicAdd(&sa[128 + c], u2f(EBpk[0][cl]));
    }
}

// ---------------------------------------------------------------------------
// K2: final BN + residual + relu from raw sums -> fp32 out. grid 512 x 256.
// ---------------------------------------------------------------------------
__global__ __launch_bounds__(256) void bn_kernel(
    const float* __restrict__ agg, const float* __restrict__ xin,
    const float* __restrict__ sa,
    const float* __restrict__ gm, const float* __restrict__ bt,
    float* __restrict__ outp)
{
    const int idx = blockIdx.x * 256 + threadIdx.x;
    const int n = idx >> 4;
    const int c = (idx & 15) * 8;
    size_t off = (size_t)n * D + c;
    const float inv = 1.f / NN;
    float v[8];
    #pragma unroll
    for (int h = 0; h < 2; ++h) {
        float4 av  = *(const float4*)&agg[off + h * 4];
        float4 xv  = *(const float4*)&xin[off + h * 4];
        float4 s1v = *(const float4*)&sa[c + h * 4];
        float4 s2v = *(const float4*)&sa[128 + c + h * 4];
        float4 gmv = *(const float4*)&gm[c + h * 4];
        float4 btv = *(const float4*)&bt[c + h * 4];
        float mu, var, rs;
        mu = s1v.x * inv; var = s2v.x * inv - mu * mu; rs = rsqrtf(var + EPSF);
        v[h*4+0] = fmaxf(0.f, fmaf((av.x - mu) * rs, gmv.x, btv.x) + xv.x);
        mu = s1v.y * inv; var = s2v.y * inv - mu * mu; rs = rsqrtf(var + EPSF);
        v[h*4+1] = fmaxf(0.f, fmaf((av.y - mu) * rs, gmv.y, btv.y) + xv.y);
        mu = s1v.z * inv; var = s2v.z * inv - mu * mu; rs = rsqrtf(var + EPSF);
        v[h*4+2] = fmaxf(0.f, fmaf((av.z - mu) * rs, gmv.z, btv.z) + xv.z);
        mu = s1v.w * inv; var = s2v.w * inv - mu * mu; rs = rsqrtf(var + EPSF);
        v[h*4+3] = fmaxf(0.f, fmaf((av.w - mu) * rs, gmv.w, btv.w) + xv.w);
    }
    *(float4*)&outp[off]     = *(float4*)&v[0];
    *(float4*)&outp[off + 4] = *(float4*)&v[4];
}

// ---------------------------------------------------------------------------
extern "C" void kernel_launch(void* const* d_in, const int* in_sizes, int n_in,
                              void* d_out, int out_size, void* d_ws, size_t ws_size,
                              hipStream_t stream) {
    const float* x0      = (const float*)d_in[0];
    const float* centers = (const float*)d_in[1];
    // d_in[2], d_in[3]: edge lists — clique structure is deterministic, unused.
    const float* Wf1 = (const float*)d_in[4];
    const float* bf1 = (const float*)d_in[5];
    const float* Ws1 = (const float*)d_in[6];
    const float* bs1 = (const float*)d_in[7];
    const float* gm1 = (const float*)d_in[8];
    const float* bt1 = (const float*)d_in[9];
    const float* Wf2 = (const float*)d_in[10];
    const float* bf2 = (const float*)d_in[11];
    const float* Ws2 = (const float*)d_in[12];
    const float* bs2 = (const float*)d_in[13];
    const float* gm2 = (const float*)d_in[14];
    const float* bt2 = (const float*)d_in[15];

    const size_t ND = (size_t)NN * D;              // 1048576
    unsigned short* ws_u = (unsigned short*)d_ws;
    unsigned short* WT = ws_u;                     // 2 x 65536 bf16
    float* fbase = (float*)(WT + 2 * 65536);       // 16B-aligned
    float* agg   = fbase;                          // ND
    float* x1    = fbase + ND;                     // ND
    float* sacc  = fbase + 2 * ND;                 // 2 layers x 256

    float* outp = (float*)d_out;

    cvt_kernel<<<dim3(65), dim3(256), 0, stream>>>(
        Wf1, Ws1, Wf2, Ws2, WT, sacc);

    // Layer 1 (no fused BN)
    prep_edge<<<dim3(1024), dim3(256), 0, stream>>>(
        x0, nullptr, nullptr, nullptr, nullptr, x1,
        WT, centers, Wf1, bf1, Ws1, bs1, agg, sacc);

    // Layer 2 (fuses layer-1 BN+residual+relu on the A-load; q==0 writes x1)
    prep_edge<<<dim3(1024), dim3(256), 0, stream>>>(
        x0, agg, sacc, gm1, bt1, x1,
        WT + 65536, centers, Wf2, bf2, Ws2, bs2, agg, sacc + 256);

    // Final BN
    bn_kernel<<<dim3(512), dim3(256), 0, stream>>>(
        agg, x1, sacc + 256, gm2, bt2, outp);
}

// Round 12
// 149.519 us; speedup vs baseline: 2.4391x; 1.0250x over previous
//
#include <hip/hip_runtime.h>
#include <hip/hip_bf16.h>

#define NSAMP 128
#define AGENTS 64
#define D 128
#define NN (NSAMP * AGENTS)      // 8192
#define LOG2E 1.44269504088896340736f
#define LN2   0.69314718055994530942f
#define EPSF  1e-5f

typedef __attribute__((ext_vector_type(8))) short short8;
typedef __attribute__((ext_vector_type(4))) float floatx4;

__device__ __forceinline__ float u2f(unsigned v) {
    float f; __builtin_memcpy(&f, &v, 4); return f;
}
__device__ __forceinline__ unsigned short f2bf(float f) {
    unsigned x; __builtin_memcpy(&x, &f, 4);
    return (unsigned short)((x + 0x7FFFu + ((x >> 16) & 1u)) >> 16);
}

// ---------------------------------------------------------------------------
// K0: build transposed bf16 weights WT[layer][arr][c][k]=Wside[k][c];
//     arr: 0=Af(dst) 1=Bf(src) 2=As(dst) 3=Bs(src). Block 64 zeros sacc.
// grid 65 x 256.
// ---------------------------------------------------------------------------
__global__ __launch_bounds__(256) void cvt_kernel(
    const float* __restrict__ Wf1, const float* __restrict__ Ws1,
    const float* __restrict__ Wf2, const float* __restrict__ Ws2,
    unsigned short* __restrict__ WT, float* __restrict__ sacc)
{
    int t = blockIdx.x, tid = threadIdx.x;
    if (t < 64) {
        int rr = t * 16 + (tid >> 4);        // layer*512 + arr*128 + c
        int kk = (tid & 15) * 8;
        int layer = rr >> 9, rem = rr & 511, arr = rem >> 7, c = rem & 127;
        const float* M = (arr < 2) ? (layer ? Wf2 : Wf1) : (layer ? Ws2 : Ws1);
        int side = arr & 1;                  // 0: W rows 0:128 (dst), 1: 128:256 (src)
        short8 sv;
        #pragma unroll
        for (int j = 0; j < 8; ++j)
            sv[j] = (short)f2bf(M[(size_t)(side * 128 + kk + j) * D + c]);
        *(short8*)&WT[(size_t)(layer * 4 + arr) * 16384 + c * 128 + kk] = sv;
    } else {
        sacc[tid]       = 0.f;
        sacc[256 + tid] = 0.f;
    }
}

// ---------------------------------------------------------------------------
// K1: fused prep (MFMA) + edge aggregation, channel-sliced.
// Block = (sample-pair, 16-col slice q); grid 512 = 64 pairs x 8 slices;
// 512 threads (8 waves), __launch_bounds__(512,4) -> 128 VGPR cap,
// 2 blocks/CU x 8 waves = 16 waves/CU. LDS 17.4 KB.
// Phase A: wave w -> sample (w>>2), mtile (w&3): 16 rows x 16 cols x 4 gate
//   arrays via MFMA 16x16x32 bf16; exp2 -> packed bf16 pairs (low=f, high=s)
//   stored TRANSPOSED in LDS: E*[smp][cl][row] so phase B reads rows with
//   ds_read_b128 (4 j per load).
//   Layouts (verified): A[m=lane&15][k=quad*8+j]; B[k][n=lane&15] from
//   WT[n][k]; C/D col=lane&15, row=quad*4+reg.
// Phase B: thread=(cl, slot 0..31): sample slot>>4, 4 dst rows (slot&15)*4..;
//   j-loop 16 x b128 (4 packed src gates each):
//   agg[d][c] = sum_{j!=d} rcp(1+EAf*EBf)*log2(1+EAs*EBs)*ln2
//   (full sum, exact self-cancel). Stats: 32-slot tree -> atomicAdd sacc.
// ---------------------------------------------------------------------------
__global__ __launch_bounds__(512, 4) void prep_edge(
    const float* __restrict__ xin,           // [NN][128] fp32
    const unsigned short* __restrict__ WTl,  // [4][128][128] bf16, this layer
    const float* __restrict__ centers,       // [NN][2]
    const float* __restrict__ Wf, const float* __restrict__ bfp,
    const float* __restrict__ Ws, const float* __restrict__ bsp,
    float* __restrict__ agg,                 // [NN][D] fp32
    float* __restrict__ sa)                  // [2][128] s1,s2
{
    const int s0 = (blockIdx.x >> 3) * 2, q = blockIdx.x & 7;
    const int tid = threadIdx.x;
    const int w = tid >> 6, lane = tid & 63;
    const int quad = lane >> 4, l16 = lane & 15;
    const int col = q * 16 + l16;

    __shared__ unsigned int EApk[2][16][68];   // [smp][cl][row], stride 68
    __shared__ unsigned int EBpk[2][16][68];

    // ---- Phase A: wave w -> sample w>>2, mtile w&3 ----
    {
        const int smp = w >> 2, m = w & 3;
        const int nbase = (s0 + smp) * AGENTS;
        short8 a[4];
        {
            const float* xr = xin + (size_t)(nbase + m * 16 + l16) * D + quad * 8;
            #pragma unroll
            for (int kc = 0; kc < 4; ++kc) {
                float4 v0 = *(const float4*)(xr + kc * 32);
                float4 v1 = *(const float4*)(xr + kc * 32 + 4);
                short8 tv;
                tv[0] = (short)f2bf(v0.x); tv[1] = (short)f2bf(v0.y);
                tv[2] = (short)f2bf(v0.z); tv[3] = (short)f2bf(v0.w);
                tv[4] = (short)f2bf(v1.x); tv[5] = (short)f2bf(v1.y);
                tv[6] = (short)f2bf(v1.z); tv[7] = (short)f2bf(v1.w);
                a[kc] = tv;
            }
        }
        floatx4 acc[4];
        #pragma unroll
        for (int arr = 0; arr < 4; ++arr) {
            const unsigned short* wp = WTl + ((size_t)arr * 128 + col) * 128 + quad * 8;
            floatx4 ac = {0.f, 0.f, 0.f, 0.f};
            #pragma unroll
            for (int kc = 0; kc < 4; ++kc)
                ac = __builtin_amdgcn_mfma_f32_16x16x32_bf16(
                    a[kc], *(const short8*)(wp + kc * 32), ac, 0, 0, 0);
            acc[arr] = ac;
        }
        const float cwf0 = Wf[256 * D + col], cwf1 = Wf[257 * D + col];
        const float cws0 = Ws[256 * D + col], cws1 = Ws[257 * D + col];
        const float bfv = bfp[col], bsv = bsp[col];
        #pragma unroll
        for (int r = 0; r < 4; ++r) {
            int row = m * 16 + quad * 4 + r;
            int n = nbase + row;
            float ce0 = centers[2 * n], ce1 = centers[2 * n + 1];
            float ctf = fmaf(ce0, cwf0, ce1 * cwf1);
            float cts = fmaf(ce0, cws0, ce1 * cws1);
            unsigned eafu = (unsigned)f2bf(__builtin_amdgcn_exp2f(-LOG2E * (acc[0][r] + ctf + bfv)));
            unsigned easu = (unsigned)f2bf(__builtin_amdgcn_exp2f( LOG2E * (acc[2][r] + cts + bsv)));
            unsigned ebfu = (unsigned)f2bf(__builtin_amdgcn_exp2f(-LOG2E * (acc[1][r] - ctf)));
            unsigned ebsu = (unsigned)f2bf(__builtin_amdgcn_exp2f( LOG2E * (acc[3][r] - cts)));
            EApk[smp][l16][row] = eafu | (easu << 16);
            EBpk[smp][l16][row] = ebfu | (ebsu << 16);
        }
    }
    __syncthreads();

    // ---- Phase B: thread=(cl, slot 0..31); sample slot>>4, 4 dst rows ----
    const int cl = tid & 15, slot = tid >> 4;
    const int smpB = slot >> 4;
    const int r0 = (slot & 15) * 4;
    const int nb2 = (s0 + smpB) * AGENTS;
    const int c = q * 16 + cl;

    float eaf[4], eas[4], ac2[4];
    {
        uint4 ea4 = *(const uint4*)&EApk[smpB][cl][r0];
        unsigned ew[4] = {ea4.x, ea4.y, ea4.z, ea4.w};
        #pragma unroll
        for (int i = 0; i < 4; ++i) {
            eaf[i] = u2f(ew[i] << 16);
            eas[i] = u2f(ew[i] & 0xFFFF0000u);
            ac2[i] = 0.f;
        }
    }
    #pragma unroll 2
    for (int jb = 0; jb < 16; ++jb) {
        uint4 pk4 = *(const uint4*)&EBpk[smpB][cl][jb * 4];
        unsigned pkw[4] = {pk4.x, pk4.y, pk4.z, pk4.w};
        #pragma unroll
        for (int jj = 0; jj < 4; ++jj) {
            float ebf = u2f(pkw[jj] << 16);
            float ebs = u2f(pkw[jj] & 0xFFFF0000u);
            #pragma unroll
            for (int i = 0; i < 4; ++i) {
                float sg = __builtin_amdgcn_rcpf(fmaf(eaf[i], ebf, 1.f));
                float lg = __builtin_amdgcn_logf(fmaf(eas[i], ebs, 1.f));
                ac2[i] = fmaf(sg, lg, ac2[i]);
            }
        }
    }
    float s1 = 0.f, s2 = 0.f;
    {
        uint4 sd4 = *(const uint4*)&EBpk[smpB][cl][r0];
        unsigned sw[4] = {sd4.x, sd4.y, sd4.z, sd4.w};
        #pragma unroll
        for (int i = 0; i < 4; ++i) {
            float ebf = u2f(sw[i] << 16);
            float ebs = u2f(sw[i] & 0xFFFF0000u);
            float sg = __builtin_amdgcn_rcpf(fmaf(eaf[i], ebf, 1.f));
            float lg = __builtin_amdgcn_logf(fmaf(eas[i], ebs, 1.f));
            float v = (ac2[i] - sg * lg) * LN2;   // exact self-cancel
            agg[(size_t)(nb2 + r0 + i) * D + c] = v;
            s1 += v; s2 += v * v;
        }
    }
    __syncthreads();                           // all gate reads done; reuse LDS
    float* red1 = (float*)&EApk[0][0][0];      // 512 floats
    float* red2 = (float*)&EBpk[0][0][0];
    red1[slot * 16 + cl] = s1;
    red2[slot * 16 + cl] = s2;
    __syncthreads();
    #pragma unroll
    for (int off = 16; off >= 1; off >>= 1) {
        if (slot < off) {
            red1[slot * 16 + cl] += red1[(slot + off) * 16 + cl];
            red2[slot * 16 + cl] += red2[(slot + off) * 16 + cl];
        }
        __syncthreads();
    }
    if (slot == 0) {
        atomicAdd(&sa[c],       red1[cl]);
        atomicAdd(&sa[128 + c], red2[cl]);
    }
}

// ---------------------------------------------------------------------------
// K2: BN + residual + relu from raw sums -> fp32 out. grid 512 x 256.
// ---------------------------------------------------------------------------
__global__ __launch_bounds__(256) void bn_kernel(
    const float* __restrict__ agg, const float* __restrict__ xin,
    const float* __restrict__ sa,
    const float* __restrict__ gm, const float* __restrict__ bt,
    float* __restrict__ outp)
{
    const int idx = blockIdx.x * 256 + threadIdx.x;
    const int n = idx >> 4;
    const int c = (idx & 15) * 8;
    size_t off = (size_t)n * D + c;
    const float inv = 1.f / NN;
    float v[8];
    #pragma unroll
    for (int h = 0; h < 2; ++h) {
        float4 av  = *(const float4*)&agg[off + h * 4];
        float4 xv  = *(const float4*)&xin[off + h * 4];
        float4 s1v = *(const float4*)&sa[c + h * 4];
        float4 s2v = *(const float4*)&sa[128 + c + h * 4];
        float4 gmv = *(const float4*)&gm[c + h * 4];
        float4 btv = *(const float4*)&bt[c + h * 4];
        float mu, var, rs;
        mu = s1v.x * inv; var = s2v.x * inv - mu * mu; rs = rsqrtf(var + EPSF);
        v[h*4+0] = fmaxf(0.f, fmaf((av.x - mu) * rs, gmv.x, btv.x) + xv.x);
        mu = s1v.y * inv; var = s2v.y * inv - mu * mu; rs = rsqrtf(var + EPSF);
        v[h*4+1] = fmaxf(0.f, fmaf((av.y - mu) * rs, gmv.y, btv.y) + xv.y);
        mu = s1v.z * inv; var = s2v.z * inv - mu * mu; rs = rsqrtf(var + EPSF);
        v[h*4+2] = fmaxf(0.f, fmaf((av.z - mu) * rs, gmv.z, btv.z) + xv.z);
        mu = s1v.w * inv; var = s2v.w * inv - mu * mu; rs = rsqrtf(var + EPSF);
        v[h*4+3] = fmaxf(0.f, fmaf((av.w - mu) * rs, gmv.w, btv.w) + xv.w);
    }
    *(float4*)&outp[off]     = *(float4*)&v[0];
    *(float4*)&outp[off + 4] = *(float4*)&v[4];
}

// ---------------------------------------------------------------------------
extern "C" void kernel_launch(void* const* d_in, const int* in_sizes, int n_in,
                              void* d_out, int out_size, void* d_ws, size_t ws_size,
                              hipStream_t stream) {
    const float* x0      = (const float*)d_in[0];
    const float* centers = (const float*)d_in[1];
    // d_in[2], d_in[3]: edge lists — clique structure is deterministic, unused.
    const float* Wf1 = (const float*)d_in[4];
    const float* bf1 = (const float*)d_in[5];
    const float* Ws1 = (const float*)d_in[6];
    const float* bs1 = (const float*)d_in[7];
    const float* gm1 = (const float*)d_in[8];
    const float* bt1 = (const float*)d_in[9];
    const float* Wf2 = (const float*)d_in[10];
    const float* bf2 = (const float*)d_in[11];
    const float* Ws2 = (const float*)d_in[12];
    const float* bs2 = (const float*)d_in[13];
    const float* gm2 = (const float*)d_in[14];
    const float* bt2 = (const float*)d_in[15];

    const size_t ND = (size_t)NN * D;              // 1048576
    unsigned short* ws_u = (unsigned short*)d_ws;
    unsigned short* WT = ws_u;                     // 2 x 65536 bf16
    float* fbase = (float*)(WT + 2 * 65536);       // 16B-aligned
    float* agg   = fbase;                          // ND
    float* x1    = fbase + ND;                     // ND
    float* sacc  = fbase + 2 * ND;                 // 2 layers x 256

    float* outp = (float*)d_out;

    cvt_kernel<<<dim3(65), dim3(256), 0, stream>>>(
        Wf1, Ws1, Wf2, Ws2, WT, sacc);

    // Layer 1
    prep_edge<<<dim3(512), dim3(512), 0, stream>>>(
        x0, WT, centers, Wf1, bf1, Ws1, bs1, agg, sacc);
    bn_kernel<<<dim3(512), dim3(256), 0, stream>>>(
        agg, x0, sacc, gm1, bt1, x1);

    // Layer 2
    prep_edge<<<dim3(512), dim3(512), 0, stream>>>(
        x1, WT + 65536, centers, Wf2, bf2, Ws2, bs2, agg, sacc + 256);
    bn_kernel<<<dim3(512), dim3(256), 0, stream>>>(
        agg, x1, sacc + 256, gm2, bt2, outp);
}